// Round 2
// baseline (702.029 us; speedup 1.0000x reference)
//
#include <hip/hip_runtime.h>
#include <hip/hip_bf16.h>
#include <cstdint>
#include <cstddef>

// LoRALinear: out[T,M] = x[T,N] @ (W + A@B^T)^T + b      (alpha = 8/8 = 1)
// T=8192, M=4096, N=4096, RANK=8, all fp32 in/out.
//
// Round-2 structure:
//   out = x @ Wh^T + b + (x@B) @ A^T
//   - pass 1 (fused): x -> f16 cast  AND  xB[t][r] = sum_n x[t][n]*B[n][r]
//   - pass 2: W -> f16 cast (pure streaming, no rank-8 work)
//   - pass 3: m97-style 128x128 f16 MFMA GEMM; rank-8 delta applied in the
//             epilogue in fp32 (reads xB + A, both L1-resident).

#define T_DIM 8192
#define M_DIM 4096
#define N_DIM 4096
#define RANK  8

typedef _Float16 f16x8 __attribute__((ext_vector_type(8)));
typedef float    f32x4 __attribute__((ext_vector_type(4)));

// ---------------------------------------------------------------- pass 1
// One block per token row t. 256 threads x 16 consecutive n each.
// Produces Xh (f16) and xB[t][0..7] (fp32).
__global__ __launch_bounds__(256)
void fuse_x(const float* __restrict__ x, const float* __restrict__ B,
            _Float16* __restrict__ xh, float* __restrict__ xB) {
    __shared__ float sred[4][8];
    const int t   = blockIdx.x;
    const int tid = threadIdx.x;
    const int n0  = tid * 16;

    const float* xrow = x + (size_t)t * N_DIM + n0;
    f32x4 xv[4];
#pragma unroll
    for (int k = 0; k < 4; ++k) xv[k] = *(const f32x4*)(xrow + k * 4);

    // cast -> f16, two 16B stores
    f16x8 h0, h1;
#pragma unroll
    for (int k = 0; k < 4; ++k) h0[k] = (_Float16)xv[0][k];
#pragma unroll
    for (int k = 0; k < 4; ++k) h0[4 + k] = (_Float16)xv[1][k];
#pragma unroll
    for (int k = 0; k < 4; ++k) h1[k] = (_Float16)xv[2][k];
#pragma unroll
    for (int k = 0; k < 4; ++k) h1[4 + k] = (_Float16)xv[3][k];
    *(f16x8*)(xh + (size_t)t * N_DIM + n0)     = h0;
    *(f16x8*)(xh + (size_t)t * N_DIM + n0 + 8) = h1;

    // partial xB over this thread's 16 n (B rows are contiguous 512B)
    const float* Bp = B + (size_t)n0 * RANK;
    f32x4 acc0 = {0.f, 0.f, 0.f, 0.f}, acc1 = {0.f, 0.f, 0.f, 0.f};
#pragma unroll
    for (int nn = 0; nn < 16; ++nn) {
        const float xs = ((const float*)xv)[nn];
        f32x4 b0 = *(const f32x4*)(Bp + nn * RANK);
        f32x4 b1 = *(const f32x4*)(Bp + nn * RANK + 4);
        acc0 += xs * b0;
        acc1 += xs * b1;
    }

    // wave reduce (64 lanes), then cross-wave via LDS
    float v[8];
#pragma unroll
    for (int k = 0; k < 4; ++k) { v[k] = acc0[k]; v[4 + k] = acc1[k]; }
#pragma unroll
    for (int off = 32; off > 0; off >>= 1)
#pragma unroll
        for (int k = 0; k < 8; ++k) v[k] += __shfl_down(v[k], off);
    const int lane = tid & 63, wave = tid >> 6;
    if (lane < 8) sred[wave][lane] = 0.f;   // pre-clear unnecessary; overwritten
    if (lane == 0)
#pragma unroll
        for (int k = 0; k < 8; ++k) sred[wave][k] = v[k];
    __syncthreads();
    if (tid < 8)
        xB[(size_t)t * RANK + tid] =
            sred[0][tid] + sred[1][tid] + sred[2][tid] + sred[3][tid];
}

// ---------------------------------------------------------------- pass 2
// pure fp32 -> f16 streaming cast (used for W)
__global__ __launch_bounds__(256)
void cvt_f16(const float* __restrict__ src, _Float16* __restrict__ dst) {
    size_t i = ((size_t)blockIdx.x * blockDim.x + threadIdx.x) * 8;
    f32x4 v0 = *(const f32x4*)(src + i);
    f32x4 v1 = *(const f32x4*)(src + i + 4);
    f16x8 o;
#pragma unroll
    for (int k = 0; k < 4; ++k) { o[k] = (_Float16)v0[k]; o[4 + k] = (_Float16)v1[k]; }
    *(f16x8*)(dst + i) = o;
}

// ---------------------------------------------------------------- GEMM
__device__ static inline void gld_lds16(const void* g, void* l) {
    __builtin_amdgcn_global_load_lds(
        (const __attribute__((address_space(1))) unsigned int*)g,
        (__attribute__((address_space(3))) unsigned int*)l, 16, 0, 0);
}

__global__ __launch_bounds__(256, 2)
void gemm_f16(const _Float16* __restrict__ X, const _Float16* __restrict__ Wt,
              const float* __restrict__ bias, const float* __restrict__ A,
              const float* __restrict__ xB, float* __restrict__ out) {
    // contiguous [128][32] f16 tiles — no padding (global_load_lds constraint)
    __shared__ __align__(16) _Float16 lA[128 * 32];
    __shared__ __align__(16) _Float16 lB[128 * 32];

    const int tid  = threadIdx.x;
    const int lane = tid & 63;
    const int wave = tid >> 6;
    const int wr = wave >> 1, wc = wave & 1;
    const int bx = blockIdx.x, by = blockIdx.y;

    const size_t rowX0 = (size_t)by * 128;
    const size_t rowW0 = (size_t)bx * 128;

    const int srow = tid >> 2;
    const int scol = (tid & 3) << 3;
    const int fr = lane & 15;
    const int fk = (lane >> 4) << 3;

    f32x4 acc[4][4] = {};

    for (int k0 = 0; k0 < N_DIM; k0 += 32) {
        gld_lds16(X  + (rowX0      + srow) * N_DIM + k0 + scol, &lA[tid * 8]);
        gld_lds16(X  + (rowX0 + 64 + srow) * N_DIM + k0 + scol, &lA[2048 + tid * 8]);
        gld_lds16(Wt + (rowW0      + srow) * N_DIM + k0 + scol, &lB[tid * 8]);
        gld_lds16(Wt + (rowW0 + 64 + srow) * N_DIM + k0 + scol, &lB[2048 + tid * 8]);
        asm volatile("s_waitcnt vmcnt(0)" ::: "memory");
        __syncthreads();

        f16x8 af[4], bf[4];
#pragma unroll
        for (int i = 0; i < 4; ++i)
            af[i] = *(const f16x8*)&lA[(wr * 64 + i * 16 + fr) * 32 + fk];
#pragma unroll
        for (int i = 0; i < 4; ++i)
            bf[i] = *(const f16x8*)&lB[(wc * 64 + i * 16 + fr) * 32 + fk];
#pragma unroll
        for (int i = 0; i < 4; ++i)
#pragma unroll
            for (int j = 0; j < 4; ++j)
                acc[i][j] = __builtin_amdgcn_mfma_f32_16x16x32_f16(
                    af[i], bf[j], acc[i][j], 0, 0, 0);
        __syncthreads();
    }

    // epilogue: C/D col = lane&15 (out col m), row = (lane>>4)*4 + reg
    const int crow0 = by * 128 + wr * 64;
    const int ccol0 = bx * 128 + wc * 64;

    f32x4 Ac0[4], Ac1[4];
    float bv[4];
    int   colv[4];
#pragma unroll
    for (int j = 0; j < 4; ++j) {
        const int col = ccol0 + j * 16 + (lane & 15);
        colv[j] = col;
        bv[j]   = bias[col];
        Ac0[j]  = *(const f32x4*)(A + (size_t)col * RANK);
        Ac1[j]  = *(const f32x4*)(A + (size_t)col * RANK + 4);
    }
#pragma unroll
    for (int i = 0; i < 4; ++i) {
#pragma unroll
        for (int r = 0; r < 4; ++r) {
            const int row = crow0 + i * 16 + ((lane >> 4) << 2) + r;
            f32x4 xb0 = *(const f32x4*)(xB + (size_t)row * RANK);
            f32x4 xb1 = *(const f32x4*)(xB + (size_t)row * RANK + 4);
#pragma unroll
            for (int j = 0; j < 4; ++j) {
                float d = xb0[0] * Ac0[j][0] + xb0[1] * Ac0[j][1]
                        + xb0[2] * Ac0[j][2] + xb0[3] * Ac0[j][3]
                        + xb1[0] * Ac1[j][0] + xb1[1] * Ac1[j][1]
                        + xb1[2] * Ac1[j][2] + xb1[3] * Ac1[j][3];
                out[(size_t)row * M_DIM + colv[j]] = acc[i][j][r] + bv[j] + d;
            }
        }
    }
}

// ---------------------------------------------------------------- launch
extern "C" void kernel_launch(void* const* d_in, const int* in_sizes, int n_in,
                              void* d_out, int out_size, void* d_ws, size_t ws_size,
                              hipStream_t stream) {
    const float* x = (const float*)d_in[0];
    const float* W = (const float*)d_in[1];
    const float* b = (const float*)d_in[2];
    const float* A = (const float*)d_in[3];
    const float* B = (const float*)d_in[4];
    float* out = (float*)d_out;

    // ws: [Wh f16 32MB][Xh f16 64MB][xB f32 256KB]
    _Float16* Wh = (_Float16*)d_ws;
    _Float16* Xh = (_Float16*)((char*)d_ws + (size_t)M_DIM * N_DIM * 2);
    float*    xB = (float*)   ((char*)d_ws + (size_t)M_DIM * N_DIM * 2
                                           + (size_t)T_DIM * N_DIM * 2);

    fuse_x<<<T_DIM, 256, 0, stream>>>(x, B, Xh, xB);
    cvt_f16<<<((size_t)M_DIM * N_DIM / 8) / 256, 256, 0, stream>>>(W, Wh);

    dim3 grid(M_DIM / 128, T_DIM / 128);
    gemm_f16<<<grid, dim3(256, 1, 1), 0, stream>>>(Xh, Wh, b, A, xB, out);
}

// Round 3
// 635.040 us; speedup vs baseline: 1.1055x; 1.1055x over previous
//
#include <hip/hip_runtime.h>
#include <hip/hip_bf16.h>
#include <cstdint>
#include <cstddef>

// LoRALinear: out[T,M] = x[T,N] @ (W + A@B^T)^T + b      (alpha = 8/8 = 1)
// T=8192, M=4096, N=4096, RANK=8, all fp32 in/out.
//
// Round-3: same structure as round 2 (out = x@Wh^T + b + (x@B)@A^T) but
// fuse_x's dot phase uses a lane-consecutive n mapping so B reads are
// contiguous 2KB per wave instruction (round 1/2 prep was killed by
// 512B-lane-stride B gathers: 64 cache lines per wave load).

#define T_DIM 8192
#define M_DIM 4096
#define N_DIM 4096
#define RANK  8

typedef _Float16 f16x8 __attribute__((ext_vector_type(8)));
typedef float    f32x4 __attribute__((ext_vector_type(4)));

// ---------------------------------------------------------------- pass 1
// One block per token row t. Phase A: coalesced f32x4 loads of the row,
// cast -> f16 (thread tid owns n = tid*16..+16, 64B contiguous).
// Phase B: xB[t][r] dot — thread tid owns n = k*256+tid (k=0..15): B loads
// are lane-stride 32B (contiguous 2KB/wave), x re-read is scalar coalesced
// and L1-hot (the row was just streamed in phase A).
__global__ __launch_bounds__(256)
void fuse_x(const float* __restrict__ x, const float* __restrict__ B,
            _Float16* __restrict__ xh, float* __restrict__ xB) {
    __shared__ float sred[4][8];
    const int t   = blockIdx.x;
    const int tid = threadIdx.x;

    // ---- phase A: cast
    {
        const int n0 = tid * 16;
        const float* xrow = x + (size_t)t * N_DIM + n0;
        f32x4 xv[4];
#pragma unroll
        for (int k = 0; k < 4; ++k) xv[k] = *(const f32x4*)(xrow + k * 4);
        f16x8 h0, h1;
#pragma unroll
        for (int k = 0; k < 4; ++k) { h0[k] = (_Float16)xv[0][k]; h0[4 + k] = (_Float16)xv[1][k]; }
#pragma unroll
        for (int k = 0; k < 4; ++k) { h1[k] = (_Float16)xv[2][k]; h1[4 + k] = (_Float16)xv[3][k]; }
        *(f16x8*)(xh + (size_t)t * N_DIM + n0)     = h0;
        *(f16x8*)(xh + (size_t)t * N_DIM + n0 + 8) = h1;
    }

    // ---- phase B: xB dot, lane-consecutive n
    f32x4 acc0 = {0.f, 0.f, 0.f, 0.f}, acc1 = {0.f, 0.f, 0.f, 0.f};
    const float* xrow = x + (size_t)t * N_DIM;
#pragma unroll
    for (int k = 0; k < 16; ++k) {
        const int n = k * 256 + tid;
        const float xs = xrow[n];                       // coalesced scalar, L1-hot
        const float* Brow = B + (size_t)n * RANK;       // lane-stride 32B: 2KB/wave
        f32x4 b0 = *(const f32x4*)(Brow);
        f32x4 b1 = *(const f32x4*)(Brow + 4);
        acc0 += xs * b0;
        acc1 += xs * b1;
    }

    // wave reduce (64 lanes) then cross-wave via LDS
    float v[8];
#pragma unroll
    for (int k = 0; k < 4; ++k) { v[k] = acc0[k]; v[4 + k] = acc1[k]; }
#pragma unroll
    for (int off = 32; off > 0; off >>= 1)
#pragma unroll
        for (int k = 0; k < 8; ++k) v[k] += __shfl_down(v[k], off);
    const int lane = tid & 63, wave = tid >> 6;
    if (lane == 0)
#pragma unroll
        for (int k = 0; k < 8; ++k) sred[wave][k] = v[k];
    __syncthreads();
    if (tid < 8)
        xB[(size_t)t * RANK + tid] =
            sred[0][tid] + sred[1][tid] + sred[2][tid] + sred[3][tid];
}

// ---------------------------------------------------------------- pass 2
// pure fp32 -> f16 streaming cast (used for W)
__global__ __launch_bounds__(256)
void cvt_f16(const float* __restrict__ src, _Float16* __restrict__ dst) {
    size_t i = ((size_t)blockIdx.x * blockDim.x + threadIdx.x) * 8;
    f32x4 v0 = *(const f32x4*)(src + i);
    f32x4 v1 = *(const f32x4*)(src + i + 4);
    f16x8 o;
#pragma unroll
    for (int k = 0; k < 4; ++k) { o[k] = (_Float16)v0[k]; o[4 + k] = (_Float16)v1[k]; }
    *(f16x8*)(dst + i) = o;
}

// ---------------------------------------------------------------- GEMM
__device__ static inline void gld_lds16(const void* g, void* l) {
    __builtin_amdgcn_global_load_lds(
        (const __attribute__((address_space(1))) unsigned int*)g,
        (__attribute__((address_space(3))) unsigned int*)l, 16, 0, 0);
}

__global__ __launch_bounds__(256, 2)
void gemm_f16(const _Float16* __restrict__ X, const _Float16* __restrict__ Wt,
              const float* __restrict__ bias, const float* __restrict__ A,
              const float* __restrict__ xB, float* __restrict__ out) {
    // contiguous [128][32] f16 tiles — no padding (global_load_lds constraint)
    __shared__ __align__(16) _Float16 lA[128 * 32];
    __shared__ __align__(16) _Float16 lB[128 * 32];

    const int tid  = threadIdx.x;
    const int lane = tid & 63;
    const int wave = tid >> 6;
    const int wr = wave >> 1, wc = wave & 1;
    const int bx = blockIdx.x, by = blockIdx.y;

    const size_t rowX0 = (size_t)by * 128;
    const size_t rowW0 = (size_t)bx * 128;

    const int srow = tid >> 2;
    const int scol = (tid & 3) << 3;
    const int fr = lane & 15;
    const int fk = (lane >> 4) << 3;

    f32x4 acc[4][4] = {};

    for (int k0 = 0; k0 < N_DIM; k0 += 32) {
        gld_lds16(X  + (rowX0      + srow) * N_DIM + k0 + scol, &lA[tid * 8]);
        gld_lds16(X  + (rowX0 + 64 + srow) * N_DIM + k0 + scol, &lA[2048 + tid * 8]);
        gld_lds16(Wt + (rowW0      + srow) * N_DIM + k0 + scol, &lB[tid * 8]);
        gld_lds16(Wt + (rowW0 + 64 + srow) * N_DIM + k0 + scol, &lB[2048 + tid * 8]);
        asm volatile("s_waitcnt vmcnt(0)" ::: "memory");
        __syncthreads();

        f16x8 af[4], bf[4];
#pragma unroll
        for (int i = 0; i < 4; ++i)
            af[i] = *(const f16x8*)&lA[(wr * 64 + i * 16 + fr) * 32 + fk];
#pragma unroll
        for (int i = 0; i < 4; ++i)
            bf[i] = *(const f16x8*)&lB[(wc * 64 + i * 16 + fr) * 32 + fk];
#pragma unroll
        for (int i = 0; i < 4; ++i)
#pragma unroll
            for (int j = 0; j < 4; ++j)
                acc[i][j] = __builtin_amdgcn_mfma_f32_16x16x32_f16(
                    af[i], bf[j], acc[i][j], 0, 0, 0);
        __syncthreads();
    }

    // epilogue: C/D col = lane&15 (out col m), row = (lane>>4)*4 + reg
    const int crow0 = by * 128 + wr * 64;
    const int ccol0 = bx * 128 + wc * 64;

    f32x4 Ac0[4], Ac1[4];
    float bv[4];
    int   colv[4];
#pragma unroll
    for (int j = 0; j < 4; ++j) {
        const int col = ccol0 + j * 16 + (lane & 15);
        colv[j] = col;
        bv[j]   = bias[col];
        Ac0[j]  = *(const f32x4*)(A + (size_t)col * RANK);
        Ac1[j]  = *(const f32x4*)(A + (size_t)col * RANK + 4);
    }
#pragma unroll
    for (int i = 0; i < 4; ++i) {
#pragma unroll
        for (int r = 0; r < 4; ++r) {
            const int row = crow0 + i * 16 + ((lane >> 4) << 2) + r;
            f32x4 xb0 = *(const f32x4*)(xB + (size_t)row * RANK);
            f32x4 xb1 = *(const f32x4*)(xB + (size_t)row * RANK + 4);
#pragma unroll
            for (int j = 0; j < 4; ++j) {
                float d = xb0[0] * Ac0[j][0] + xb0[1] * Ac0[j][1]
                        + xb0[2] * Ac0[j][2] + xb0[3] * Ac0[j][3]
                        + xb1[0] * Ac1[j][0] + xb1[1] * Ac1[j][1]
                        + xb1[2] * Ac1[j][2] + xb1[3] * Ac1[j][3];
                out[(size_t)row * M_DIM + colv[j]] = acc[i][j][r] + bv[j] + d;
            }
        }
    }
}

// ---------------------------------------------------------------- launch
extern "C" void kernel_launch(void* const* d_in, const int* in_sizes, int n_in,
                              void* d_out, int out_size, void* d_ws, size_t ws_size,
                              hipStream_t stream) {
    const float* x = (const float*)d_in[0];
    const float* W = (const float*)d_in[1];
    const float* b = (const float*)d_in[2];
    const float* A = (const float*)d_in[3];
    const float* B = (const float*)d_in[4];
    float* out = (float*)d_out;

    // ws: [Wh f16 32MB][Xh f16 64MB][xB f32 256KB]
    _Float16* Wh = (_Float16*)d_ws;
    _Float16* Xh = (_Float16*)((char*)d_ws + (size_t)M_DIM * N_DIM * 2);
    float*    xB = (float*)   ((char*)d_ws + (size_t)M_DIM * N_DIM * 2
                                           + (size_t)T_DIM * N_DIM * 2);

    fuse_x<<<T_DIM, 256, 0, stream>>>(x, B, Xh, xB);
    cvt_f16<<<((size_t)M_DIM * N_DIM / 8) / 256, 256, 0, stream>>>(W, Wh);

    dim3 grid(M_DIM / 128, T_DIM / 128);
    gemm_f16<<<grid, dim3(256, 1, 1), 0, stream>>>(Xh, Wh, b, A, xB, out);
}